// Round 16
// baseline (669.839 us; speedup 1.0000x reference)
//
#include <hip/hip_runtime.h>
#include <cfloat>
#include <math.h>

#define N 96
#define DIN 16
#define HID 256
#define LAT 128
#define EDGE 4656
#define OUTDIM 6192

typedef unsigned long long ull;

// ---- ws float offsets ----
enum {
  WH1   = 0,            // 96*256
  WX1   = 24576,        // 96*256
  WH2   = 49152,        // 96*256
  WGH   = 73728,        // 256
  WKL   = 73984,        // 4
  WOUTP = 73988,        // 4656
  WOUTX = 78644,        // 1536
  WDEGT = 80180,        // 96
  WDEGR = 80276,        // 96
  WDT   = 80372,        // 96
  WDR   = 80468,        // 96
  WMSK  = 98996,        // 192 ull = 384 floats (8B aligned)
  WXA   = 99380,        // 96*104 row-major padded
  WXB   = 109364,       // 96*104
  WXAT  = 119348,       // 96*96  col-major (xT[a][i] = x[i][a])
  WXBT  = 128564,       // 96*96
  WSSP  = 137780        // 2 * 96*4 per-wave norm^2 partials (ping-pong)
};

__device__ __forceinline__ int triidx(int i, int j) { // requires i<=j
  return i * N - (i * (i - 1)) / 2 + (j - i);
}

// DPP wave64 reduce steps (pure VALU) — validated R9-R15 (absmax 0)
#define FMAXDPP(m, ctrl, rmask)                                                    \
  { int _d = __builtin_amdgcn_update_dpp(__float_as_int(m), __float_as_int(m),     \
                                         (ctrl), (rmask), 0xF, false);             \
    m = fmaxf(m, __int_as_float(_d)); }

// top-2 insert by (value desc, index asc)
#define INS2(vv, ii) { if ((vv) > M1 || ((vv) == M1 && (ii) < A1)) { M2 = M1; A2 = A1; M1 = (vv); A1 = (ii); } \
                       else if ((vv) > M2 || ((vv) == M2 && (ii) < A2)) { M2 = (vv); A2 = (ii); } }

// vectorized top-2 row scan: 4 dual-slot chains + 8-candidate merge.
// first-index tie-break exact for BOTH slots.
__device__ __forceinline__ void scan_row2(const float* __restrict__ Xrow,
                                          float& m1o, int& a1o,
                                          float& m2o, int& a2o, bool& q2o) {
  const float4* xr4 = (const float4*)Xrow;
  float p1x = -FLT_MAX, p1y = -FLT_MAX, p1z = -FLT_MAX, p1w = -FLT_MAX;
  float p2x = -FLT_MAX, p2y = -FLT_MAX, p2z = -FLT_MAX, p2w = -FLT_MAX;
  int b1x = 0, b1y = 1, b1z = 2, b1w = 3;
  int b2x = 0, b2y = 1, b2z = 2, b2w = 3;
#pragma unroll
  for (int q = 0; q < 24; ++q) {
    float4 v = xr4[q];
    if (v.x > p1x) { p2x = p1x; b2x = b1x; p1x = v.x; b1x = 4 * q; }
    else if (v.x > p2x) { p2x = v.x; b2x = 4 * q; }
    if (v.y > p1y) { p2y = p1y; b2y = b1y; p1y = v.y; b1y = 4 * q + 1; }
    else if (v.y > p2y) { p2y = v.y; b2y = 4 * q + 1; }
    if (v.z > p1z) { p2z = p1z; b2z = b1z; p1z = v.z; b1z = 4 * q + 2; }
    else if (v.z > p2z) { p2z = v.z; b2z = 4 * q + 2; }
    if (v.w > p1w) { p2w = p1w; b2w = b1w; p1w = v.w; b1w = 4 * q + 3; }
    else if (v.w > p2w) { p2w = v.w; b2w = 4 * q + 3; }
  }
  float M1 = -FLT_MAX, M2 = -FLT_MAX; int A1 = 0, A2 = 0;
  INS2(p1x, b1x); INS2(p2x, b2x);
  INS2(p1y, b1y); INS2(p2y, b2y);
  INS2(p1z, b1z); INS2(p2z, b2z);
  INS2(p1w, b1w); INS2(p2w, b2w);
  m1o = M1; a1o = A1; m2o = M2; a2o = A2; q2o = (M2 != -FLT_MAX);
}

// ---- h1 = (adj @ feats) @ conv1_w ; block=row i, 256 thr ----
__global__ void k_enc1(const float* __restrict__ adj, const float* __restrict__ feats,
                       const float* __restrict__ w1, float* __restrict__ h1) {
  int i = blockIdx.x, t = threadIdx.x;
  __shared__ float p[16][17];
  __shared__ float t1[16];
  int k = t & 15, part = t >> 4;
  float s = 0.f;
  for (int j = part * 6; j < part * 6 + 6; ++j) s += adj[i * N + j] * feats[j * DIN + k];
  p[part][k] = s;
  __syncthreads();
  if (t < 16) { float q = 0.f; for (int r = 0; r < 16; ++r) q += p[r][t]; t1[t] = q; }
  __syncthreads();
  float h = 0.f;
  for (int kk = 0; kk < 16; ++kk) h += t1[kk] * w1[kk * HID + t];
  h1[i * HID + t] = h;
}

// ---- BN1 + ReLU ; block=col c, 128 thr ----
__global__ void k_bn1(const float* __restrict__ h1, const float* __restrict__ gg,
                      const float* __restrict__ bb, float* __restrict__ x1) {
  int c = blockIdx.x, t = threadIdx.x;
  float v = (t < N) ? h1[t * HID + c] : 0.f;
  __shared__ float s1[128], s2[128];
  s1[t] = v; s2[t] = v * v; __syncthreads();
  for (int s = 64; s > 0; s >>= 1) { if (t < s) { s1[t] += s1[t + s]; s2[t] += s2[t + s]; } __syncthreads(); }
  float mu = s1[0] / (float)N;
  float var = s2[0] / (float)N - mu * mu;
  float inv = rsqrtf(var + 1e-5f);
  if (t < N) x1[t * HID + c] = fmaxf((v - mu) * inv * gg[c] + bb[c], 0.f);
}

// ---- h2 = (adj @ x1) @ conv2_w ; block=row i, 256 thr ----
__global__ void k_enc2(const float* __restrict__ adj, const float* __restrict__ x1,
                       const float* __restrict__ w2, float* __restrict__ h2) {
  int i = blockIdx.x, t = threadIdx.x;
  __shared__ float t2[HID];
  float s = 0.f;
  for (int j = 0; j < N; ++j) s += adj[i * N + j] * x1[j * HID + t];
  t2[t] = s;
  __syncthreads();
  float h = 0.f;
  for (int k = 0; k < HID; ++k) h += t2[k] * w2[k * HID + t];
  h2[i * HID + t] = h;
}

// ---- BN2 then gh = column sums ; block=col c ----
__global__ void k_bn2gh(const float* __restrict__ h2, const float* __restrict__ gg,
                        const float* __restrict__ bb, float* __restrict__ gh) {
  int c = blockIdx.x, t = threadIdx.x;
  float v = (t < N) ? h2[t * HID + c] : 0.f;
  __shared__ float s1[128], s2[128];
  s1[t] = v; s2[t] = v * v; __syncthreads();
  for (int s = 64; s > 0; s >>= 1) { if (t < s) { s1[t] += s1[t + s]; s2[t] += s2[t + s]; } __syncthreads(); }
  float mu = s1[0] / (float)N;
  float var = s2[0] / (float)N - mu * mu;
  float inv = rsqrtf(var + 1e-5f);
  __syncthreads();
  float xv = (t < N) ? ((v - mu) * inv * gg[c] + bb[c]) : 0.f;
  s1[t] = xv; __syncthreads();
  for (int s = 64; s > 0; s >>= 1) { if (t < s) s1[t] += s1[t + s]; __syncthreads(); }
  if (t == 0) gh[c] = s1[0];
}

// ---- VAE (redundant per block) + decoder ; 25 blocks x 256 thr ----
__global__ void k_vaedec(const float* __restrict__ gh,
                         const float* __restrict__ e11w, const float* __restrict__ e11b,
                         const float* __restrict__ e12w, const float* __restrict__ e12b,
                         const float* __restrict__ d1w, const float* __restrict__ d1b,
                         const float* __restrict__ d2w, const float* __restrict__ d2b,
                         const float* __restrict__ eps, float* __restrict__ kl,
                         float* __restrict__ outp, float* __restrict__ outx) {
  int t = threadIdx.x;
  __shared__ float ghs[HID], zs[LAT], h1d[LAT], kr[LAT];
  ghs[t] = gh[t];
  __syncthreads();
  if (t < LAT) {
    float a = e11b[t], c = e12b[t];
    for (int k = 0; k < HID; ++k) {
      float g = ghs[k];
      a = fmaf(e11w[t * HID + k], g, a);
      c = fmaf(e12w[t * HID + k], g, c);
    }
    zs[t] = eps[t] * expf(0.5f * c) + a;
    kr[t] = 1.f + c - a * a - expf(c);
  }
  __syncthreads();
  if (blockIdx.x == 0 && t == 0) {
    float s = 0.f;
    for (int k = 0; k < LAT; ++k) s += kr[k];
    kl[0] = -0.5f * s / (float)(N * N);
  }
  if (t < LAT) {
    float hv = d1b[t];
    for (int k = 0; k < LAT; ++k) hv = fmaf(d1w[t * LAT + k], zs[k], hv);
    h1d[t] = fmaxf(hv, 0.f);
  }
  __syncthreads();
  int o = blockIdx.x * 256 + t;
  if (o < OUTDIM) {
    const float4* wr = (const float4*)(d2w + o * LAT);
    float s = d2b[o];
    for (int k4 = 0; k4 < 32; ++k4) {
      float4 v = wr[k4];
      s = fmaf(v.x, h1d[k4 * 4], fmaf(v.y, h1d[k4 * 4 + 1],
            fmaf(v.z, h1d[k4 * 4 + 2], fmaf(v.w, h1d[k4 * 4 + 3], s))));
    }
    if (o < EDGE) outp[o] = 1.f / (1.f + expf(-s));
    else outx[o - EDGE] = s;
  }
}

// ---- degrees, diagonals, bitmasks, x0 init ; block=row a, 128 thr ----
__global__ void k_prep(const float* __restrict__ adj, const float* __restrict__ outp,
                       float* __restrict__ degt, float* __restrict__ degr,
                       float* __restrict__ dt, float* __restrict__ dr,
                       ull* __restrict__ mskg, float* __restrict__ x0,
                       float* __restrict__ x0T) {
  int a = blockIdx.x, t = threadIdx.x;
  float rv = 0.f, av = 0.f;
  if (t < N) {
    int i2 = min(a, t), j2 = max(a, t);
    rv = outp[triidx(i2, j2)];
    av = adj[a * N + t];
    if (t == a) { dr[a] = rv; dt[a] = av; }
  }
  ull bal = __ballot(t < N && av > 0.5f);
  if ((t & 63) == 0) mskg[a * 2 + (t >> 6)] = bal;
  if (t < 104) x0[a * 104 + t] = 1.f / (float)N;
  if (t < N) x0T[a * N + t] = 1.f / (float)N;
  __shared__ float s1[128], s2[128];
  s1[t] = rv; s2[t] = av; __syncthreads();
  for (int s = 64; s > 0; s >>= 1) { if (t < s) { s1[t] += s1[t + s]; s2[t] += s2[t + s]; } __syncthreads(); }
  if (t == 0) { degr[a] = s1[0]; degt[a] = s2[0]; }
}

// ---- one MPM iteration ; block = column a, 256 thr (2 threads per row) ----
// 2 barriers; norm^2 partials written per-wave to global (consumer sums 4).
__global__ __launch_bounds__(256) void k_mpm(
    const float* __restrict__ xin,  const float* __restrict__ xinT,
    float* __restrict__ xout, float* __restrict__ xoutT,
    const float* __restrict__ outp,
    const float* __restrict__ degt, const float* __restrict__ degr,
    const float* __restrict__ dt, const float* __restrict__ dr,
    const ull* __restrict__ mskg,
    const float* __restrict__ sspP, float* __restrict__ sspC, int first) {
  const int a = blockIdx.x, t = threadIdx.x;
  const int w = t >> 6, l = t & 63;
  const int j = t >> 1, h = t & 1;          // row j, half h (b in [48h,48h+48))
  __shared__ __align__(16) float Bs[96];
  __shared__ float Ms[96];
  __shared__ float red[4];
  const bool act = (j < N);
  const float drA = dr[a];
  const float dgrA = degr[a];
  if (t < N) {
    int i2 = min(a, t), j2 = max(a, t);
    float rv = outp[triidx(i2, j2)];
    Bs[t] = (t == a) ? 0.f : rv * drA * dr[t];
  }
  float sv = 0.f;
  if (!first && t < N) {
    float4 s4 = *(const float4*)(sspP + t * 4);
    sv = s4.x + s4.y + s4.z + s4.w;
  }
#pragma unroll
  for (int off = 32; off >= 1; off >>= 1) sv += __shfl_xor(sv, off);
  if (l == 0) red[w] = sv;
  ull wm = 0;
  if (act) {
    wm = mskg[j * 2 + h];
    if (h == 0) { if (j < 64) wm &= ~(1ull << j); }
    else        { if (j >= 64) wm &= ~(1ull << (j - 64)); }
  }
  __syncthreads();
  const float inv = first ? 1.f : rsqrtf(red[0] + red[1] + red[2] + red[3]);
  if (act) {
    const float4* xr = (const float4*)(xin + j * 104) + h * 12;
    const float4* Bs4 = (const float4*)Bs + h * 12;
    float m0 = 0.f;
#pragma unroll
    for (int k = 0; k < 12; ++k) {
      float4 xq = xr[k];
      float4 bq = Bs4[k];
      m0 = fmaxf(m0, fmaxf(fmaxf(bq.x * xq.x, bq.y * xq.y),
                           fmaxf(bq.z * xq.z, bq.w * xq.w)));
    }
    m0 = fmaxf(m0, __shfl_xor(m0, 1));
    if (h == 0) Ms[j] = m0;
  }
  __syncthreads();
  float ss = 0.f;
  if (act) {
    float macc = 0.f;
    ull mm = wm;
    int base = h * 64;
    while (mm) { int jj = __builtin_ctzll(mm); mm &= mm - 1; macc += Ms[base + jj]; }
    macc += __shfl_xor(macc, 1);
    if (h == 0) {
      float sd = dt[j] * drA / (fabsf(degt[j] - dgrA) + 1.f);
      float v = fmaf(xinT[a * N + j], sd, macc) * inv;
      xout[j * 104 + a] = v;
      xoutT[a * N + j] = v;
      ss = v * v;
    }
  }
#pragma unroll
  for (int off = 32; off >= 1; off >>= 1) ss += __shfl_xor(ss, off);
  if (l == 0) sspC[a * 4 + w] = ss;     // per-wave partial (wave3 writes 0)
}

// ---- greedy (row-per-thread, top-2 cache, DPP max + ballot, 1 barrier/step) ----
__global__ __launch_bounds__(128) void k_fin(
    const float* __restrict__ xfin,      // [96][104] row-major
    const ull* __restrict__ mskg,
    const float* __restrict__ feats,
    const float* __restrict__ outp, const float* __restrict__ outx,
    const float* __restrict__ kl, float* __restrict__ out) {
  int t = threadIdx.x;
  int w = t >> 6, l = t & 63;
  __shared__ float X[96 * 100];
  __shared__ int INDS[96];
  __shared__ ull MSKl[192];
  __shared__ float kwM[2][2];
  __shared__ int kwI[2][2];
  __shared__ float rf[2], rb[2];

  // fused: load own row global->LDS while computing top-2
  bool alive = (t < N);
  float mT = -FLT_MAX, mS = -FLT_MAX;
  int aT = 0, aS = 0;
  bool qS = false;
  if (alive) {
    const float4* src = (const float4*)&xfin[t * 104];
    float4* dst = (float4*)&X[t * 100];
    float p1x = -FLT_MAX, p1y = -FLT_MAX, p1z = -FLT_MAX, p1w = -FLT_MAX;
    float p2x = -FLT_MAX, p2y = -FLT_MAX, p2z = -FLT_MAX, p2w = -FLT_MAX;
    int b1x = 0, b1y = 1, b1z = 2, b1w = 3;
    int b2x = 0, b2y = 1, b2z = 2, b2w = 3;
#pragma unroll
    for (int q = 0; q < 24; ++q) {
      float4 v = src[q];
      dst[q] = v;
      if (v.x > p1x) { p2x = p1x; b2x = b1x; p1x = v.x; b1x = 4 * q; }
      else if (v.x > p2x) { p2x = v.x; b2x = 4 * q; }
      if (v.y > p1y) { p2y = p1y; b2y = b1y; p1y = v.y; b1y = 4 * q + 1; }
      else if (v.y > p2y) { p2y = v.y; b2y = 4 * q + 1; }
      if (v.z > p1z) { p2z = p1z; b2z = b1z; p1z = v.z; b1z = 4 * q + 2; }
      else if (v.z > p2z) { p2z = v.z; b2z = 4 * q + 2; }
      if (v.w > p1w) { p2w = p1w; b2w = b1w; p1w = v.w; b1w = 4 * q + 3; }
      else if (v.w > p2w) { p2w = v.w; b2w = 4 * q + 3; }
    }
    float M1 = -FLT_MAX, M2 = -FLT_MAX; int A1 = 0, A2 = 0;
    INS2(p1x, b1x); INS2(p2x, b2x);
    INS2(p1y, b1y); INS2(p2y, b2y);
    INS2(p1z, b1z); INS2(p2z, b2z);
    INS2(p1w, b1w); INS2(p2w, b2w);
    mT = M1; aT = A1; mS = M2; aS = A2; qS = (M2 != -FLT_MAX);
  }
  if (t < 96) { MSKl[2 * t] = mskg[2 * t]; MSKl[2 * t + 1] = mskg[2 * t + 1]; }
  __syncthreads();

  for (int step = 0; step < N; ++step) {
    // per-wave value max (pure VALU DPP)
    float vc = alive ? mT : -FLT_MAX;
    FMAXDPP(vc, 0x111, 0xF);   // row_shr:1
    FMAXDPP(vc, 0x112, 0xF);   // row_shr:2
    FMAXDPP(vc, 0x114, 0xF);   // row_shr:4
    FMAXDPP(vc, 0x118, 0xF);   // row_shr:8
    FMAXDPP(vc, 0x142, 0xA);   // row_bcast15
    FMAXDPP(vc, 0x143, 0xC);   // row_bcast31
    float Mw = __int_as_float(__builtin_amdgcn_readlane(__float_as_int(vc), 63));
    // winner lane = lowest lane with mT==Mw (rows ascend with lane -> smallest flat)
    ull b = __ballot(alive && mT == Mw);
    int wl = (b == 0) ? 0 : (int)__builtin_ctzll(b);
    int sl = step & 1;
    if (l == wl) kwI[sl][w] = (b == 0) ? 0x7FFFFFFF : (t * N + aT);
    if (l == 0) kwM[sl][w] = Mw;
    __syncthreads();
    float M0 = kwM[sl][0], M1v = kwM[sl][1];
    int F = (M1v > M0) ? kwI[sl][1] : kwI[sl][0];   // tie -> wave0 (smaller flats)
    int r = F / N, c = F - (F / N) * N;
    if (t == r) { INDS[c] = r; alive = false; }
    if (t < N) X[t * 100 + c] = -FLT_MAX;           // own-row clear (no hazard)
    if (alive) {
      if (aT == c) {
        if (qS) { mT = mS; aT = aS; qS = false; }   // exact promotion (aS alive by invariant)
        else scan_row2(&X[t * 100], mT, aT, mS, aS, qS);  // rare full rescan
      } else if (qS && aS == c) {
        qS = false;                                 // keep invariant: qS => aS alive
      }
    }
  }
  __syncthreads();

  // ---- losses ----
  float accf = 0.f;
  for (int p = t; p < N * DIN; p += 128) {
    int i = p >> 4, k = p & 15;
    float d = outx[p] - feats[INDS[i] * DIN + k];
    accf += d * d;
  }
  float accb = 0.f;
  for (int e = t; e < EDGE; e += 128) {
    int i = (int)((193.0f - sqrtf(193.0f * 193.0f - 8.0f * (float)e)) * 0.5f);
    if (i < 0) i = 0; if (i > 95) i = 95;
    while (i < 95 && triidx(i + 1, i + 1) <= e) ++i;
    while (i > 0 && triidx(i, i) > e) --i;
    int j = i + (e - triidx(i, i));
    int ri = INDS[i], rj = INDS[j];
    float tv = (float)((MSKl[ri * 2 + (rj >> 6)] >> (rj & 63)) & 1ull);
    float pr = outp[e];
    float l1 = fmaxf(logf(pr), -100.f);
    float l0 = fmaxf(log1pf(-pr), -100.f);
    accb += tv * l1 + (1.f - tv) * l0;
  }
#pragma unroll
  for (int off = 32; off >= 1; off >>= 1) { accf += __shfl_xor(accf, off); accb += __shfl_xor(accb, off); }
  if (l == 0) { rf[w] = accf; rb[w] = accb; }
  __syncthreads();
  if (t == 0) {
    float ff = rf[0] + rf[1];
    float bb = rb[0] + rb[1];
    out[0] = (-bb / (float)EDGE) + kl[0] + ff / (float)(N * DIN);
  }
}

extern "C" void kernel_launch(void* const* d_in, const int* in_sizes, int n_in,
                              void* d_out, int out_size, void* d_ws, size_t ws_size,
                              hipStream_t stream) {
  const float* feats = (const float*)d_in[0];
  const float* adj   = (const float*)d_in[1];
  const float* w1    = (const float*)d_in[2];
  const float* w2    = (const float*)d_in[3];
  const float* bn1g  = (const float*)d_in[4];
  const float* bn1b  = (const float*)d_in[5];
  const float* bn2g  = (const float*)d_in[6];
  const float* bn2b  = (const float*)d_in[7];
  const float* e11w  = (const float*)d_in[8];
  const float* e11b  = (const float*)d_in[9];
  const float* e12w  = (const float*)d_in[10];
  const float* e12b  = (const float*)d_in[11];
  const float* d1w   = (const float*)d_in[12];
  const float* d1b   = (const float*)d_in[13];
  const float* d2w   = (const float*)d_in[14];
  const float* d2b   = (const float*)d_in[15];
  const float* eps   = (const float*)d_in[16];

  float* ws   = (float*)d_ws;
  float* h1   = ws + WH1;
  float* x1   = ws + WX1;
  float* h2   = ws + WH2;
  float* gh   = ws + WGH;
  float* kl   = ws + WKL;
  float* outp = ws + WOUTP;
  float* outx = ws + WOUTX;
  float* degt = ws + WDEGT;
  float* degr = ws + WDEGR;
  float* dt   = ws + WDT;
  float* dr   = ws + WDR;
  ull*   mskg = (ull*)(ws + WMSK);
  float* xa   = ws + WXA;
  float* xb   = ws + WXB;
  float* xaT  = ws + WXAT;
  float* xbT  = ws + WXBT;
  float* ssp  = ws + WSSP;
  float* out  = (float*)d_out;

  k_enc1<<<96, 256, 0, stream>>>(adj, feats, w1, h1);
  k_bn1<<<256, 128, 0, stream>>>(h1, bn1g, bn1b, x1);
  k_enc2<<<96, 256, 0, stream>>>(adj, x1, w2, h2);
  k_bn2gh<<<256, 128, 0, stream>>>(h2, bn2g, bn2b, gh);
  k_vaedec<<<25, 256, 0, stream>>>(gh, e11w, e11b, e12w, e12b, d1w, d1b,
                                   d2w, d2b, eps, kl, outp, outx);
  k_prep<<<96, 128, 0, stream>>>(adj, outp, degt, degr, dt, dr, mskg, xa, xaT);

  for (int m = 0; m < 50; ++m) {
    const float* xi  = (m & 1) ? xb : xa;
    const float* xiT = (m & 1) ? xbT : xaT;
    float* xo        = (m & 1) ? xa : xb;
    float* xoT       = (m & 1) ? xaT : xbT;
    float* sc        = ssp + (m & 1) * 384;
    const float* sp  = ssp + ((m & 1) ^ 1) * 384;
    k_mpm<<<96, 256, 0, stream>>>(xi, xiT, xo, xoT, outp, degt, degr, dt, dr,
                                  mskg, sp, sc, (m == 0) ? 1 : 0);
  }
  // m=49 odd -> final x in xa
  k_fin<<<1, 128, 0, stream>>>(xa, mskg, feats, outp, outx, kl, out);
}

// Round 17
// 453.798 us; speedup vs baseline: 1.4761x; 1.4761x over previous
//
#include <hip/hip_runtime.h>
#include <cfloat>
#include <math.h>

#define N 96
#define DIN 16
#define HID 256
#define LAT 128
#define EDGE 4656
#define OUTDIM 6192

typedef unsigned long long ull;

// ---- ws float offsets ----
enum {
  WH1   = 0,            // 96*256
  WX1   = 24576,        // 96*256
  WH2   = 49152,        // 96*256
  WGH   = 73728,        // 256
  WKL   = 73984,        // 4
  WOUTP = 73988,        // 4656
  WOUTX = 78644,        // 1536
  WDEGT = 80180,        // 96
  WDEGR = 80276,        // 96
  WDT   = 80372,        // 96
  WDR   = 80468,        // 96
  WMSK  = 98996,        // 192 ull = 384 floats (8B aligned)
  WXA   = 99380,        // 96*104 row-major padded
  WXB   = 109364,       // 96*104
  WXAT  = 119348,       // 96*96  col-major (xT[a][i] = x[i][a])
  WXBT  = 128564,       // 96*96
  WSSP  = 137780        // 2 * 96*4 per-wave norm^2 partials (ping-pong)
};

__device__ __forceinline__ int triidx(int i, int j) { // requires i<=j
  return i * N - (i * (i - 1)) / 2 + (j - i);
}

// DPP wave64 reduce steps (pure VALU) — validated R9-R16 (absmax 0)
#define FMAXDPP(m, ctrl, rmask)                                                    \
  { int _d = __builtin_amdgcn_update_dpp(__float_as_int(m), __float_as_int(m),     \
                                         (ctrl), (rmask), 0xF, false);             \
    m = fmaxf(m, __int_as_float(_d)); }

// 4-chain row scan: first-flat-index tie-break (validated R10/R14)
__device__ __forceinline__ void scan_row(const float* __restrict__ Xrow,
                                         float& mOut, int& aOut) {
  const float4* xr4 = (const float4*)Xrow;
  float m0 = -FLT_MAX, m1 = -FLT_MAX, m2 = -FLT_MAX, m3 = -FLT_MAX;
  int a0 = 0, a1 = 1, a2 = 2, a3 = 3;
#pragma unroll
  for (int q = 0; q < 24; ++q) {
    float4 v = xr4[q];
    if (v.x > m0) { m0 = v.x; a0 = 4 * q; }
    if (v.y > m1) { m1 = v.y; a1 = 4 * q + 1; }
    if (v.z > m2) { m2 = v.z; a2 = 4 * q + 2; }
    if (v.w > m3) { m3 = v.w; a3 = 4 * q + 3; }
  }
  if (m1 > m0 || (m1 == m0 && a1 < a0)) { m0 = m1; a0 = a1; }
  if (m3 > m2 || (m3 == m2 && a3 < a2)) { m2 = m3; a2 = a3; }
  if (m2 > m0 || (m2 == m0 && a2 < a0)) { m0 = m2; a0 = a2; }
  mOut = m0; aOut = a0;
}

// ---- h1 = (adj @ feats) @ conv1_w ; block=row i, 256 thr ----
__global__ void k_enc1(const float* __restrict__ adj, const float* __restrict__ feats,
                       const float* __restrict__ w1, float* __restrict__ h1) {
  int i = blockIdx.x, t = threadIdx.x;
  __shared__ float p[16][17];
  __shared__ float t1[16];
  int k = t & 15, part = t >> 4;
  float s = 0.f;
  for (int j = part * 6; j < part * 6 + 6; ++j) s += adj[i * N + j] * feats[j * DIN + k];
  p[part][k] = s;
  __syncthreads();
  if (t < 16) { float q = 0.f; for (int r = 0; r < 16; ++r) q += p[r][t]; t1[t] = q; }
  __syncthreads();
  float h = 0.f;
  for (int kk = 0; kk < 16; ++kk) h += t1[kk] * w1[kk * HID + t];
  h1[i * HID + t] = h;
}

// ---- BN1 + ReLU ; block=col c, 128 thr ----
__global__ void k_bn1(const float* __restrict__ h1, const float* __restrict__ gg,
                      const float* __restrict__ bb, float* __restrict__ x1) {
  int c = blockIdx.x, t = threadIdx.x;
  float v = (t < N) ? h1[t * HID + c] : 0.f;
  __shared__ float s1[128], s2[128];
  s1[t] = v; s2[t] = v * v; __syncthreads();
  for (int s = 64; s > 0; s >>= 1) { if (t < s) { s1[t] += s1[t + s]; s2[t] += s2[t + s]; } __syncthreads(); }
  float mu = s1[0] / (float)N;
  float var = s2[0] / (float)N - mu * mu;
  float inv = rsqrtf(var + 1e-5f);
  if (t < N) x1[t * HID + c] = fmaxf((v - mu) * inv * gg[c] + bb[c], 0.f);
}

// ---- h2 = (adj @ x1) @ conv2_w ; block=row i, 256 thr ----
__global__ void k_enc2(const float* __restrict__ adj, const float* __restrict__ x1,
                       const float* __restrict__ w2, float* __restrict__ h2) {
  int i = blockIdx.x, t = threadIdx.x;
  __shared__ float t2[HID];
  float s = 0.f;
  for (int j = 0; j < N; ++j) s += adj[i * N + j] * x1[j * HID + t];
  t2[t] = s;
  __syncthreads();
  float h = 0.f;
  for (int k = 0; k < HID; ++k) h += t2[k] * w2[k * HID + t];
  h2[i * HID + t] = h;
}

// ---- BN2 then gh = column sums ; block=col c ----
__global__ void k_bn2gh(const float* __restrict__ h2, const float* __restrict__ gg,
                        const float* __restrict__ bb, float* __restrict__ gh) {
  int c = blockIdx.x, t = threadIdx.x;
  float v = (t < N) ? h2[t * HID + c] : 0.f;
  __shared__ float s1[128], s2[128];
  s1[t] = v; s2[t] = v * v; __syncthreads();
  for (int s = 64; s > 0; s >>= 1) { if (t < s) { s1[t] += s1[t + s]; s2[t] += s2[t + s]; } __syncthreads(); }
  float mu = s1[0] / (float)N;
  float var = s2[0] / (float)N - mu * mu;
  float inv = rsqrtf(var + 1e-5f);
  __syncthreads();
  float xv = (t < N) ? ((v - mu) * inv * gg[c] + bb[c]) : 0.f;
  s1[t] = xv; __syncthreads();
  for (int s = 64; s > 0; s >>= 1) { if (t < s) s1[t] += s1[t + s]; __syncthreads(); }
  if (t == 0) gh[c] = s1[0];
}

// ---- VAE (redundant per block) + decoder ; 25 blocks x 256 thr ----
__global__ void k_vaedec(const float* __restrict__ gh,
                         const float* __restrict__ e11w, const float* __restrict__ e11b,
                         const float* __restrict__ e12w, const float* __restrict__ e12b,
                         const float* __restrict__ d1w, const float* __restrict__ d1b,
                         const float* __restrict__ d2w, const float* __restrict__ d2b,
                         const float* __restrict__ eps, float* __restrict__ kl,
                         float* __restrict__ outp, float* __restrict__ outx) {
  int t = threadIdx.x;
  __shared__ float ghs[HID], zs[LAT], h1d[LAT], kr[LAT];
  ghs[t] = gh[t];
  __syncthreads();
  if (t < LAT) {
    float a = e11b[t], c = e12b[t];
    for (int k = 0; k < HID; ++k) {
      float g = ghs[k];
      a = fmaf(e11w[t * HID + k], g, a);
      c = fmaf(e12w[t * HID + k], g, c);
    }
    zs[t] = eps[t] * expf(0.5f * c) + a;
    kr[t] = 1.f + c - a * a - expf(c);
  }
  __syncthreads();
  if (blockIdx.x == 0 && t == 0) {
    float s = 0.f;
    for (int k = 0; k < LAT; ++k) s += kr[k];
    kl[0] = -0.5f * s / (float)(N * N);
  }
  if (t < LAT) {
    float hv = d1b[t];
    for (int k = 0; k < LAT; ++k) hv = fmaf(d1w[t * LAT + k], zs[k], hv);
    h1d[t] = fmaxf(hv, 0.f);
  }
  __syncthreads();
  int o = blockIdx.x * 256 + t;
  if (o < OUTDIM) {
    const float4* wr = (const float4*)(d2w + o * LAT);
    float s = d2b[o];
    for (int k4 = 0; k4 < 32; ++k4) {
      float4 v = wr[k4];
      s = fmaf(v.x, h1d[k4 * 4], fmaf(v.y, h1d[k4 * 4 + 1],
            fmaf(v.z, h1d[k4 * 4 + 2], fmaf(v.w, h1d[k4 * 4 + 3], s))));
    }
    if (o < EDGE) outp[o] = 1.f / (1.f + expf(-s));
    else outx[o - EDGE] = s;
  }
}

// ---- degrees, diagonals, bitmasks, x0 init ; block=row a, 128 thr ----
__global__ void k_prep(const float* __restrict__ adj, const float* __restrict__ outp,
                       float* __restrict__ degt, float* __restrict__ degr,
                       float* __restrict__ dt, float* __restrict__ dr,
                       ull* __restrict__ mskg, float* __restrict__ x0,
                       float* __restrict__ x0T) {
  int a = blockIdx.x, t = threadIdx.x;
  float rv = 0.f, av = 0.f;
  if (t < N) {
    int i2 = min(a, t), j2 = max(a, t);
    rv = outp[triidx(i2, j2)];
    av = adj[a * N + t];
    if (t == a) { dr[a] = rv; dt[a] = av; }
  }
  ull bal = __ballot(t < N && av > 0.5f);
  if ((t & 63) == 0) mskg[a * 2 + (t >> 6)] = bal;
  if (t < 104) x0[a * 104 + t] = 1.f / (float)N;
  if (t < N) x0T[a * N + t] = 1.f / (float)N;
  __shared__ float s1[128], s2[128];
  s1[t] = rv; s2[t] = av; __syncthreads();
  for (int s = 64; s > 0; s >>= 1) { if (t < s) { s1[t] += s1[t + s]; s2[t] += s2[t + s]; } __syncthreads(); }
  if (t == 0) { degr[a] = s1[0]; degt[a] = s2[0]; }
}

// ---- one MPM iteration ; block = column a, 256 thr (2 threads per row) ----
// 2 barriers; norm^2 partials written per-wave to global (consumer sums 4).
__global__ __launch_bounds__(256) void k_mpm(
    const float* __restrict__ xin,  const float* __restrict__ xinT,
    float* __restrict__ xout, float* __restrict__ xoutT,
    const float* __restrict__ outp,
    const float* __restrict__ degt, const float* __restrict__ degr,
    const float* __restrict__ dt, const float* __restrict__ dr,
    const ull* __restrict__ mskg,
    const float* __restrict__ sspP, float* __restrict__ sspC, int first) {
  const int a = blockIdx.x, t = threadIdx.x;
  const int w = t >> 6, l = t & 63;
  const int j = t >> 1, h = t & 1;          // row j, half h (b in [48h,48h+48))
  __shared__ __align__(16) float Bs[96];
  __shared__ float Ms[96];
  __shared__ float red[4];
  const bool act = (j < N);
  const float drA = dr[a];
  const float dgrA = degr[a];
  if (t < N) {
    int i2 = min(a, t), j2 = max(a, t);
    float rv = outp[triidx(i2, j2)];
    Bs[t] = (t == a) ? 0.f : rv * drA * dr[t];
  }
  float sv = 0.f;
  if (!first && t < N) {
    float4 s4 = *(const float4*)(sspP + t * 4);
    sv = s4.x + s4.y + s4.z + s4.w;
  }
#pragma unroll
  for (int off = 32; off >= 1; off >>= 1) sv += __shfl_xor(sv, off);
  if (l == 0) red[w] = sv;
  ull wm = 0;
  if (act) {
    wm = mskg[j * 2 + h];
    if (h == 0) { if (j < 64) wm &= ~(1ull << j); }
    else        { if (j >= 64) wm &= ~(1ull << (j - 64)); }
  }
  __syncthreads();
  const float inv = first ? 1.f : rsqrtf(red[0] + red[1] + red[2] + red[3]);
  if (act) {
    const float4* xr = (const float4*)(xin + j * 104) + h * 12;
    const float4* Bs4 = (const float4*)Bs + h * 12;
    float m0 = 0.f;
#pragma unroll
    for (int k = 0; k < 12; ++k) {
      float4 xq = xr[k];
      float4 bq = Bs4[k];
      m0 = fmaxf(m0, fmaxf(fmaxf(bq.x * xq.x, bq.y * xq.y),
                           fmaxf(bq.z * xq.z, bq.w * xq.w)));
    }
    m0 = fmaxf(m0, __shfl_xor(m0, 1));
    if (h == 0) Ms[j] = m0;
  }
  __syncthreads();
  float ss = 0.f;
  if (act) {
    float macc = 0.f;
    ull mm = wm;
    int base = h * 64;
    while (mm) { int jj = __builtin_ctzll(mm); mm &= mm - 1; macc += Ms[base + jj]; }
    macc += __shfl_xor(macc, 1);
    if (h == 0) {
      float sd = dt[j] * drA / (fabsf(degt[j] - dgrA) + 1.f);
      float v = fmaf(xinT[a * N + j], sd, macc) * inv;
      xout[j * 104 + a] = v;
      xoutT[a * N + j] = v;
      ss = v * v;
    }
  }
#pragma unroll
  for (int off = 32; off >= 1; off >>= 1) ss += __shfl_xor(ss, off);
  if (l == 0) sspC[a * 4 + w] = ss;     // per-wave partial (wave3 writes 0)
}

// ---- greedy (row-per-thread, DPP value max + ballot argmin, 1 barrier/step) ----
// VERBATIM R14 (benched 156 us, absmax 0)
__global__ __launch_bounds__(128) void k_fin(
    const float* __restrict__ xfin,      // [96][104] row-major
    const ull* __restrict__ mskg,
    const float* __restrict__ feats,
    const float* __restrict__ outp, const float* __restrict__ outx,
    const float* __restrict__ kl, float* __restrict__ out) {
  int t = threadIdx.x;
  int w = t >> 6, l = t & 63;
  __shared__ float X[96 * 100];
  __shared__ int INDS[96];
  __shared__ ull MSKl[192];
  __shared__ float kwM[2][2];
  __shared__ int kwI[2][2];
  __shared__ float rf[2], rb[2];

  // fused: load own row from global -> LDS, computing initial (max, argmax)
  bool alive = (t < N);
  float mT = -FLT_MAX; int aT = 0;
  if (alive) {
    const float4* src = (const float4*)&xfin[t * 104];
    float4* dst = (float4*)&X[t * 100];
    float m0 = -FLT_MAX, m1 = -FLT_MAX, m2 = -FLT_MAX, m3 = -FLT_MAX;
    int a0 = 0, a1 = 1, a2 = 2, a3 = 3;
#pragma unroll
    for (int q = 0; q < 24; ++q) {
      float4 v = src[q];
      dst[q] = v;
      if (v.x > m0) { m0 = v.x; a0 = 4 * q; }
      if (v.y > m1) { m1 = v.y; a1 = 4 * q + 1; }
      if (v.z > m2) { m2 = v.z; a2 = 4 * q + 2; }
      if (v.w > m3) { m3 = v.w; a3 = 4 * q + 3; }
    }
    if (m1 > m0 || (m1 == m0 && a1 < a0)) { m0 = m1; a0 = a1; }
    if (m3 > m2 || (m3 == m2 && a3 < a2)) { m2 = m3; a2 = a3; }
    if (m2 > m0 || (m2 == m0 && a2 < a0)) { m0 = m2; a0 = a2; }
    mT = m0; aT = a0;
  }
  if (t < 96) { MSKl[2 * t] = mskg[2 * t]; MSKl[2 * t + 1] = mskg[2 * t + 1]; }
  __syncthreads();

  for (int step = 0; step < N; ++step) {
    // per-wave value max (pure VALU DPP)
    float vc = alive ? mT : -FLT_MAX;
    FMAXDPP(vc, 0x111, 0xF);   // row_shr:1
    FMAXDPP(vc, 0x112, 0xF);   // row_shr:2
    FMAXDPP(vc, 0x114, 0xF);   // row_shr:4
    FMAXDPP(vc, 0x118, 0xF);   // row_shr:8
    FMAXDPP(vc, 0x142, 0xA);   // row_bcast15
    FMAXDPP(vc, 0x143, 0xC);   // row_bcast31
    float Mw = __int_as_float(__builtin_amdgcn_readlane(__float_as_int(vc), 63));
    // winner lane = lowest lane with mT==Mw (rows ascend with lane -> smallest flat)
    ull b = __ballot(alive && mT == Mw);
    int wl = (b == 0) ? 0 : (int)__builtin_ctzll(b);
    int sl = step & 1;
    if (l == wl) kwI[sl][w] = (b == 0) ? 0x7FFFFFFF : (t * N + aT);
    if (l == 0) kwM[sl][w] = Mw;
    __syncthreads();
    float M0 = kwM[sl][0], M1 = kwM[sl][1];
    int F = (M1 > M0) ? kwI[sl][1] : kwI[sl][0];   // tie -> wave0 (smaller flats)
    int r = F / N, c = F - (F / N) * N;
    if (t == r) { INDS[c] = r; alive = false; }
    if (t < N) X[t * 100 + c] = -FLT_MAX;          // own-row clear (no hazard)
    if (alive && aT == c) scan_row(&X[t * 100], mT, aT);  // parallel rescan
  }
  __syncthreads();

  // ---- losses ----
  float accf = 0.f;
  for (int p = t; p < N * DIN; p += 128) {
    int i = p >> 4, k = p & 15;
    float d = outx[p] - feats[INDS[i] * DIN + k];
    accf += d * d;
  }
  float accb = 0.f;
  for (int e = t; e < EDGE; e += 128) {
    int i = (int)((193.0f - sqrtf(193.0f * 193.0f - 8.0f * (float)e)) * 0.5f);
    if (i < 0) i = 0; if (i > 95) i = 95;
    while (i < 95 && triidx(i + 1, i + 1) <= e) ++i;
    while (i > 0 && triidx(i, i) > e) --i;
    int j = i + (e - triidx(i, i));
    int ri = INDS[i], rj = INDS[j];
    float tv = (float)((MSKl[ri * 2 + (rj >> 6)] >> (rj & 63)) & 1ull);
    float pr = outp[e];
    float l1 = fmaxf(logf(pr), -100.f);
    float l0 = fmaxf(log1pf(-pr), -100.f);
    accb += tv * l1 + (1.f - tv) * l0;
  }
#pragma unroll
  for (int off = 32; off >= 1; off >>= 1) { accf += __shfl_xor(accf, off); accb += __shfl_xor(accb, off); }
  if (l == 0) { rf[w] = accf; rb[w] = accb; }
  __syncthreads();
  if (t == 0) {
    float ff = rf[0] + rf[1];
    float bb = rb[0] + rb[1];
    out[0] = (-bb / (float)EDGE) + kl[0] + ff / (float)(N * DIN);
  }
}

extern "C" void kernel_launch(void* const* d_in, const int* in_sizes, int n_in,
                              void* d_out, int out_size, void* d_ws, size_t ws_size,
                              hipStream_t stream) {
  const float* feats = (const float*)d_in[0];
  const float* adj   = (const float*)d_in[1];
  const float* w1    = (const float*)d_in[2];
  const float* w2    = (const float*)d_in[3];
  const float* bn1g  = (const float*)d_in[4];
  const float* bn1b  = (const float*)d_in[5];
  const float* bn2g  = (const float*)d_in[6];
  const float* bn2b  = (const float*)d_in[7];
  const float* e11w  = (const float*)d_in[8];
  const float* e11b  = (const float*)d_in[9];
  const float* e12w  = (const float*)d_in[10];
  const float* e12b  = (const float*)d_in[11];
  const float* d1w   = (const float*)d_in[12];
  const float* d1b   = (const float*)d_in[13];
  const float* d2w   = (const float*)d_in[14];
  const float* d2b   = (const float*)d_in[15];
  const float* eps   = (const float*)d_in[16];

  float* ws   = (float*)d_ws;
  float* h1   = ws + WH1;
  float* x1   = ws + WX1;
  float* h2   = ws + WH2;
  float* gh   = ws + WGH;
  float* kl   = ws + WKL;
  float* outp = ws + WOUTP;
  float* outx = ws + WOUTX;
  float* degt = ws + WDEGT;
  float* degr = ws + WDEGR;
  float* dt   = ws + WDT;
  float* dr   = ws + WDR;
  ull*   mskg = (ull*)(ws + WMSK);
  float* xa   = ws + WXA;
  float* xb   = ws + WXB;
  float* xaT  = ws + WXAT;
  float* xbT  = ws + WXBT;
  float* ssp  = ws + WSSP;
  float* out  = (float*)d_out;

  k_enc1<<<96, 256, 0, stream>>>(adj, feats, w1, h1);
  k_bn1<<<256, 128, 0, stream>>>(h1, bn1g, bn1b, x1);
  k_enc2<<<96, 256, 0, stream>>>(adj, x1, w2, h2);
  k_bn2gh<<<256, 128, 0, stream>>>(h2, bn2g, bn2b, gh);
  k_vaedec<<<25, 256, 0, stream>>>(gh, e11w, e11b, e12w, e12b, d1w, d1b,
                                   d2w, d2b, eps, kl, outp, outx);
  k_prep<<<96, 128, 0, stream>>>(adj, outp, degt, degr, dt, dr, mskg, xa, xaT);

  for (int m = 0; m < 50; ++m) {
    const float* xi  = (m & 1) ? xb : xa;
    const float* xiT = (m & 1) ? xbT : xaT;
    float* xo        = (m & 1) ? xa : xb;
    float* xoT       = (m & 1) ? xaT : xbT;
    float* sc        = ssp + (m & 1) * 384;
    const float* sp  = ssp + ((m & 1) ^ 1) * 384;
    k_mpm<<<96, 256, 0, stream>>>(xi, xiT, xo, xoT, outp, degt, degr, dt, dr,
                                  mskg, sp, sc, (m == 0) ? 1 : 0);
  }
  // m=49 odd -> final x in xa
  k_fin<<<1, 128, 0, stream>>>(xa, mskg, feats, outp, outx, kl, out);
}